// Round 1
// baseline (482.160 us; speedup 1.0000x reference)
//
#include <hip/hip_runtime.h>
#include <hip/hip_bf16.h>
#include <cmath>

#define NTOK 32768   // B*S
#define HDIM 512
#define GVDIM 640
#define VDIM 320
#define DG 128
#define OUT0_SIZE (NTOK * 256)

// ---------------- kernel 0: zero the histogram ----------------
__global__ void k_zero(int* __restrict__ hist) {
    hist[threadIdx.x] = 0;
}

// ---------------- kernel 1: fused GEMM + bias + argmax + histogram ----------
// grid: 1024 blocks = (32768/64 token-tiles) x 2 groups; block: 256 threads.
// lane = token (64 tokens/block). Wave w handles cols grp*320 + w*16 + c*64 + k,
// c in [0,5), k in [0,16)  -> 80 fp32 accumulators per thread.
// hs staged to LDS transposed [h][token] in two K-halves of 256.
__global__ __launch_bounds__(256) void k_gemm_argmax(
    const float* __restrict__ hs, const float* __restrict__ W,
    const float* __restrict__ bias, int* __restrict__ idx_out,
    int* __restrict__ hist)
{
    __shared__ float lds[256][65];   // 66,560 B; +1 pad -> conflict-light
    __shared__ float rval[4][64];
    __shared__ int   ridx[4][64];

    const int tid  = threadIdx.x;
    const int lane = tid & 63;
    const int wave = __builtin_amdgcn_readfirstlane(tid >> 6);
    const int tok0 = (blockIdx.x >> 1) * 64;
    const int grp  = blockIdx.x & 1;

    float acc[5][16];
#pragma unroll
    for (int c = 0; c < 5; ++c)
#pragma unroll
        for (int k = 0; k < 16; ++k) acc[c][k] = 0.0f;

    const int colbase = grp * VDIM + wave * 16;   // wave-uniform

    for (int kb = 0; kb < 2; ++kb) {
        // ---- stage 64 tokens x 256 h (coalesced float4 global reads) ----
#pragma unroll
        for (int it = 0; it < 16; ++it) {
            int f  = it * 256 + tid;          // 0..4095 float4 slots
            int t  = f >> 6;                  // token within tile
            int h4 = f & 63;                  // float4 index within K-half
            float4 v = *(const float4*)(hs + (tok0 + t) * HDIM + kb * 256 + h4 * 4);
            int h = h4 * 4;
            lds[h + 0][t] = v.x;
            lds[h + 1][t] = v.y;
            lds[h + 2][t] = v.z;
            lds[h + 3][t] = v.w;
        }
        __syncthreads();

        const float* Wb = W + (kb * 256) * GVDIM + colbase;  // wave-uniform
        for (int h = 0; h < 256; ++h) {
            float a = lds[h][lane];               // per-lane (token) activation
            const float* wr = Wb + h * GVDIM;     // uniform -> scalar loads
#pragma unroll
            for (int c = 0; c < 5; ++c) {
#pragma unroll
                for (int k = 0; k < 16; ++k)
                    acc[c][k] = fmaf(a, wr[c * 64 + k], acc[c][k]);
            }
        }
        __syncthreads();
    }

    // ---- bias + per-thread argmax (ascending idx, strict > => first max) ----
    float bv = -INFINITY;
    int   bi = 0;
#pragma unroll
    for (int c = 0; c < 5; ++c) {
#pragma unroll
        for (int k = 0; k < 16; ++k) {
            int ci = c * 64 + wave * 16 + k;          // col within group
            float v = acc[c][k] + bias[grp * VDIM + ci];
            if (v > bv) { bv = v; bi = ci; }
        }
    }
    rval[wave][lane] = bv;
    ridx[wave][lane] = bi;
    __syncthreads();

    // ---- cross-wave reduce per token; tie -> smaller index (np.argmax) ----
    if (tid < 64) {
        float v = rval[0][lane];
        int   i = ridx[0][lane];
#pragma unroll
        for (int w = 1; w < 4; ++w) {
            float v2 = rval[w][lane];
            int   i2 = ridx[w][lane];
            if (v2 > v || (v2 == v && i2 < i)) { v = v2; i = i2; }
        }
        idx_out[(tok0 + lane) * 2 + grp] = i;
        atomicAdd(&hist[grp * VDIM + i], 1);
    }
}

// ---------------- kernel 2: gather codevectors ----------------
// block 256 = 4 tokens x 64 lanes; lane -> (group, float4 slot)
__global__ __launch_bounds__(256) void k_gather(
    const float* __restrict__ cb, const int* __restrict__ idx,
    float* __restrict__ out)
{
    int tid  = threadIdx.x;
    int t    = blockIdx.x * 4 + (tid >> 6);
    int lane = tid & 63;
    int g    = lane >> 5;     // 0 or 1
    int q    = lane & 31;     // float4 slot within 128 floats
    int i    = idx[t * 2 + g];
    const float4* src = (const float4*)(cb + (g * VDIM + i) * DG);
    float4 v = src[q];
    ((float4*)(out + (size_t)t * 256))[g * 32 + q] = v;
}

// ---------------- kernel 3: perplexity from histogram ----------------
__global__ void k_perplex(const int* __restrict__ hist, float* __restrict__ out)
{
    __shared__ float sh[GVDIM];
    int t = threadIdx.x;
    float p = (float)hist[t] * (1.0f / (float)NTOK);
    sh[t] = p * logf(p + 1e-7f);
    __syncthreads();
    if (t == 0) {
        float s0 = 0.0f, s1 = 0.0f;
        for (int i = 0; i < VDIM; ++i)  s0 += sh[i];
        for (int i = VDIM; i < GVDIM; ++i) s1 += sh[i];
        out[0] = expf(-s0) + expf(-s1);
    }
}

extern "C" void kernel_launch(void* const* d_in, const int* in_sizes, int n_in,
                              void* d_out, int out_size, void* d_ws, size_t ws_size,
                              hipStream_t stream)
{
    const float* hs   = (const float*)d_in[0];
    const float* W    = (const float*)d_in[1];
    const float* bias = (const float*)d_in[2];
    const float* cb   = (const float*)d_in[3];

    int* idx  = (int*)d_ws;            // 65536 ints
    int* hist = idx + NTOK * 2;        // 640 ints

    float* out  = (float*)d_out;
    float* perp = out + OUT0_SIZE;

    hipLaunchKernelGGL(k_zero,        dim3(1),        dim3(GVDIM), 0, stream, hist);
    hipLaunchKernelGGL(k_gemm_argmax, dim3(1024),     dim3(256),   0, stream,
                       hs, W, bias, idx, hist);
    hipLaunchKernelGGL(k_gather,      dim3(NTOK / 4), dim3(256),   0, stream,
                       cb, idx, out);
    hipLaunchKernelGGL(k_perplex,     dim3(1),        dim3(GVDIM), 0, stream,
                       hist, perp);
}

// Round 2
// 228.572 us; speedup vs baseline: 2.1094x; 2.1094x over previous
//
#include <hip/hip_runtime.h>
#include <cmath>

#define NTOK 32768
#define HDIM 512
#define GVDIM 640
#define VDIM 320
#define DG 128
#define OUT0_SIZE (NTOK * 256)

typedef __attribute__((ext_vector_type(8))) short s16x8;
typedef __attribute__((ext_vector_type(8))) unsigned short u16x8;
typedef __attribute__((ext_vector_type(4))) float f32x4;

__device__ __forceinline__ unsigned short f2bf(float f) {
    unsigned u = __float_as_uint(f);
    return (unsigned short)((u + 0x7FFFu + ((u >> 16) & 1u)) >> 16);  // RTN
}

// ---------------- hist zero ----------------
__global__ void k_zero(int* __restrict__ hist) { hist[threadIdx.x] = 0; }

// ---------------- hs fp32 -> bf16 (8 elems/thread) ----------------
__global__ __launch_bounds__(256) void k_cvt_hs(const float* __restrict__ hs,
                                                unsigned short* __restrict__ dst) {
    int i = blockIdx.x * 256 + threadIdx.x;          // 2,097,152 threads
    const float4* s = (const float4*)hs + (size_t)i * 2;
    float4 a = s[0], b = s[1];
    u16x8 o;
    o[0] = f2bf(a.x); o[1] = f2bf(a.y); o[2] = f2bf(a.z); o[3] = f2bf(a.w);
    o[4] = f2bf(b.x); o[5] = f2bf(b.y); o[6] = f2bf(b.z); o[7] = f2bf(b.w);
    *((u16x8*)dst + i) = o;
}

// ---------------- W [512][640] fp32 -> Wt [640][512] bf16 ----------------
__global__ __launch_bounds__(256) void k_cvt_wt(const float* __restrict__ W,
                                                unsigned short* __restrict__ Wt) {
    int n = blockIdx.x;
#pragma unroll
    for (int k2 = 0; k2 < 2; ++k2) {
        int k = k2 * 256 + threadIdx.x;
        Wt[(size_t)n * 512 + k] = f2bf(W[(size_t)k * 640 + n]);
    }
}

// ---------------- MFMA GEMM: logits = hs_bf16 . Wt^T + bias -> fp16 ------
// 128x128 tile, BK=64, global_load_lds(16B) + XOR chunk swizzle.
__global__ __launch_bounds__(256) void k_gemm(
    const unsigned short* __restrict__ A,   // [NTOK][512] bf16
    const unsigned short* __restrict__ Bt,  // [640][512] bf16
    const float* __restrict__ bias,
    _Float16* __restrict__ logits)          // [NTOK][640]
{
    __shared__ short As[128 * 64];
    __shared__ short Bs[128 * 64];

    const int tid  = threadIdx.x;
    const int lane = tid & 63;
    const int wid  = __builtin_amdgcn_readfirstlane(tid >> 6);
    const int mb   = blockIdx.x & 255;
    const int nb   = blockIdx.x >> 8;
    const int tok0 = mb * 128;
    const int col0 = nb * 128;

    const int r8 = lane >> 3;         // row-within-8
    const int c8 = lane & 7;          // physical chunk
    const int cl = c8 ^ r8;           // logical chunk this lane fetches

    const unsigned short* gA = A  + (size_t)(tok0 + wid * 32 + r8) * 512 + cl * 8;
    const unsigned short* gB = Bt + (size_t)(col0 + wid * 32 + r8) * 512 + cl * 8;

    const int quad = lane >> 4;
    const int m16  = lane & 15;
    const int wm   = (wid >> 1) * 64;
    const int wn   = (wid & 1) * 64;

    f32x4 acc[4][4];
#pragma unroll
    for (int mt = 0; mt < 4; ++mt)
#pragma unroll
        for (int nt = 0; nt < 4; ++nt) acc[mt][nt] = (f32x4){0.f, 0.f, 0.f, 0.f};

    for (int kb = 0; kb < 8; ++kb) {
#pragma unroll
        for (int i = 0; i < 4; ++i) {
            __builtin_amdgcn_global_load_lds(
                (__attribute__((address_space(1))) void*)(gA + (size_t)i * 8 * 512 + kb * 64),
                (__attribute__((address_space(3))) void*)(As + (wid * 32 + i * 8) * 64),
                16, 0, 0);
            __builtin_amdgcn_global_load_lds(
                (__attribute__((address_space(1))) void*)(gB + (size_t)i * 8 * 512 + kb * 64),
                (__attribute__((address_space(3))) void*)(Bs + (wid * 32 + i * 8) * 64),
                16, 0, 0);
        }
        __syncthreads();
#pragma unroll
        for (int ks = 0; ks < 2; ++ks) {
            s16x8 af[4], bf[4];
            const int kch = ks * 4 + quad;
#pragma unroll
            for (int t = 0; t < 4; ++t) {
                int arow = wm + t * 16 + m16;
                af[t] = *(const s16x8*)(As + arow * 64 + (kch ^ (arow & 7)) * 8);
                int brow = wn + t * 16 + m16;
                bf[t] = *(const s16x8*)(Bs + brow * 64 + (kch ^ (brow & 7)) * 8);
            }
#pragma unroll
            for (int mt = 0; mt < 4; ++mt)
#pragma unroll
                for (int nt = 0; nt < 4; ++nt)
                    acc[mt][nt] = __builtin_amdgcn_mfma_f32_16x16x32_bf16(
                        af[mt], bf[nt], acc[mt][nt], 0, 0, 0);
        }
        __syncthreads();
    }

    float bv[4];
#pragma unroll
    for (int nt = 0; nt < 4; ++nt) bv[nt] = bias[col0 + wn + nt * 16 + m16];

#pragma unroll
    for (int mt = 0; mt < 4; ++mt) {
#pragma unroll
        for (int r = 0; r < 4; ++r) {
            int token = tok0 + wm + mt * 16 + quad * 4 + r;
            _Float16* dst = logits + (size_t)token * 640 + col0 + wn + m16;
#pragma unroll
            for (int nt = 0; nt < 4; ++nt)
                dst[nt * 16] = (_Float16)(acc[mt][nt][r] + bv[nt]);
        }
    }
}

// ---------------- argmax + exact fp32 rescore of margin candidates -------
__global__ __launch_bounds__(256) void k_argmax(
    const _Float16* __restrict__ logits, const float* __restrict__ hs,
    const float* __restrict__ W, const float* __restrict__ bias,
    int* __restrict__ idx_out, int* __restrict__ hist)
{
    const int lane = threadIdx.x & 63;
    const int wid  = threadIdx.x >> 6;
    const int tg   = blockIdx.x * 4 + wid;
    const int tok  = tg >> 1;
    const int grp  = tg & 1;

    const _Float16* lp = logits + (size_t)tok * 640 + grp * 320;
    float v[5];
#pragma unroll
    for (int j = 0; j < 5; ++j) v[j] = (float)lp[j * 64 + lane];

    float m = fmaxf(fmaxf(fmaxf(v[0], v[1]), fmaxf(v[2], v[3])), v[4]);
#pragma unroll
    for (int off = 32; off >= 1; off >>= 1) m = fmaxf(m, __shfl_xor(m, off));

    const float thr = m - 0.03f;
    unsigned long long mask[5];
    int count = 0;
#pragma unroll
    for (int j = 0; j < 5; ++j) {
        mask[j] = __ballot(v[j] >= thr);
        count += __popcll(mask[j]);
    }

    int besti = -1;
    if (count == 1) {
#pragma unroll
        for (int j = 0; j < 5; ++j)
            if (besti < 0 && mask[j]) besti = j * 64 + (__ffsll(mask[j]) - 1);
    } else {
        float hsr[8];
#pragma unroll
        for (int i = 0; i < 8; ++i) hsr[i] = hs[(size_t)tok * 512 + i * 64 + lane];
        float bestv = -INFINITY;
        for (int j = 0; j < 5; ++j) {
            unsigned long long mk = mask[j];
            while (mk) {
                int b = __ffsll(mk) - 1; mk &= mk - 1;
                int gcol = grp * 320 + j * 64 + b;
                float p = 0.f;
#pragma unroll
                for (int i = 0; i < 8; ++i)
                    p = fmaf(hsr[i], W[(size_t)(i * 64 + lane) * 640 + gcol], p);
#pragma unroll
                for (int off = 32; off >= 1; off >>= 1) p += __shfl_xor(p, off);
                float val = p + bias[gcol];
                if (val > bestv) { bestv = val; besti = j * 64 + b; }  // first-max
            }
        }
    }
    if (lane == 0) {
        idx_out[tok * 2 + grp] = besti;
        atomicAdd(&hist[grp * 320 + besti], 1);
    }
}

// ---------------- gather codevectors ----------------
__global__ __launch_bounds__(256) void k_gather(
    const float* __restrict__ cb, const int* __restrict__ idx,
    float* __restrict__ out)
{
    int tid  = threadIdx.x;
    int t    = blockIdx.x * 4 + (tid >> 6);
    int lane = tid & 63;
    int g    = lane >> 5;
    int q    = lane & 31;
    int i    = idx[t * 2 + g];
    const float4* src = (const float4*)(cb + (size_t)(g * VDIM + i) * DG);
    float4 v = src[q];
    ((float4*)(out + (size_t)t * 256))[g * 32 + q] = v;
}

// ---------------- perplexity ----------------
__global__ void k_perplex(const int* __restrict__ hist, float* __restrict__ out)
{
    __shared__ float sh[GVDIM];
    int t = threadIdx.x;
    float p = (float)hist[t] * (1.0f / (float)NTOK);
    sh[t] = p * logf(p + 1e-7f);
    __syncthreads();
    if (t == 0) {
        float s0 = 0.f, s1 = 0.f;
        for (int i = 0; i < VDIM; ++i)  s0 += sh[i];
        for (int i = VDIM; i < GVDIM; ++i) s1 += sh[i];
        out[0] = expf(-s0) + expf(-s1);
    }
}

extern "C" void kernel_launch(void* const* d_in, const int* in_sizes, int n_in,
                              void* d_out, int out_size, void* d_ws, size_t ws_size,
                              hipStream_t stream)
{
    const float* hs   = (const float*)d_in[0];
    const float* W    = (const float*)d_in[1];
    const float* bias = (const float*)d_in[2];
    const float* cb   = (const float*)d_in[3];

    unsigned short* hsb = (unsigned short*)d_ws;          // 16,777,216 bf16
    unsigned short* wt  = hsb + 16777216;                 // 327,680 bf16
    _Float16* logits    = (_Float16*)(wt + 327680);       // 20,971,520 fp16
    int* idx            = (int*)(logits + 20971520);      // 65,536 int
    int* hist           = idx + 65536;                    // 640 int

    float* out  = (float*)d_out;
    float* perp = out + OUT0_SIZE;

    hipLaunchKernelGGL(k_zero,    dim3(1),     dim3(GVDIM), 0, stream, hist);
    hipLaunchKernelGGL(k_cvt_hs,  dim3(8192),  dim3(256),   0, stream, hs, hsb);
    hipLaunchKernelGGL(k_cvt_wt,  dim3(GVDIM), dim3(256),   0, stream, W, wt);
    hipLaunchKernelGGL(k_gemm,    dim3(1280),  dim3(256),   0, stream, hsb, wt, bias, logits);
    hipLaunchKernelGGL(k_argmax,  dim3(16384), dim3(256),   0, stream, logits, hs, W, bias, idx, hist);
    hipLaunchKernelGGL(k_gather,  dim3(8192),  dim3(256),   0, stream, cb, idx, out);
    hipLaunchKernelGGL(k_perplex, dim3(1),     dim3(GVDIM), 0, stream, hist, perp);
}